// Round 3
// baseline (280.118 us; speedup 1.0000x reference)
//
#include <hip/hip_runtime.h>
#include <hip/hip_bf16.h>
#include <stdint.h>

typedef __attribute__((ext_vector_type(8))) short s16x8;           // MFMA A/B frag: 8 bf16
typedef __attribute__((ext_vector_type(4))) float f32x4;           // MFMA C/D frag / fp32 vec4
typedef __attribute__((ext_vector_type(8))) unsigned short u16x8;  // 16B vector
typedef __attribute__((ext_vector_type(4))) unsigned short u16x4;  // 8B vector

__device__ __forceinline__ float bf2f(unsigned short u) {
  union { uint32_t u; float f; } v; v.u = ((uint32_t)u) << 16; return v.f;
}
__device__ __forceinline__ unsigned short f2bf(float f) {
  union { float f; uint32_t u; } v; v.f = f;
  uint32_t u = v.u;
  return (unsigned short)((u + 0x7fffu + ((u >> 16) & 1u)) >> 16);  // RNE
}
__device__ __forceinline__ void load_lds16(const void* g, void* l) {
  __builtin_amdgcn_global_load_lds(
      (const __attribute__((address_space(1))) void*)g,
      (__attribute__((address_space(3))) void*)l, 16, 0, 0);
}

template <int N>
__device__ __forceinline__ void vmw() {
  if constexpr (N == 0) asm volatile("s_waitcnt vmcnt(0)" ::: "memory");
  else if constexpr (N == 1) asm volatile("s_waitcnt vmcnt(1)" ::: "memory");
  else if constexpr (N == 2) asm volatile("s_waitcnt vmcnt(2)" ::: "memory");
  else if constexpr (N == 3) asm volatile("s_waitcnt vmcnt(3)" ::: "memory");
  else if constexpr (N == 4) asm volatile("s_waitcnt vmcnt(4)" ::: "memory");
  else if constexpr (N == 5) asm volatile("s_waitcnt vmcnt(5)" ::: "memory");
  else if constexpr (N == 6) asm volatile("s_waitcnt vmcnt(6)" ::: "memory");
  else if constexpr (N == 7) asm volatile("s_waitcnt vmcnt(7)" ::: "memory");
  else asm volatile("s_waitcnt vmcnt(8)" ::: "memory");
}
#define SBAR() asm volatile("s_barrier" ::: "memory")

// PACKED LAYOUT: matrix [R][Kd] -> tiles 64r x 64k. Tile (rt,kt) at ushort
// offset (rt*(Kd/64)+kt)*4096; within tile: plane kb (k=kb*8+e) at kb*512,
// row r at r*8, elem e. Plane = 1 KB = one global_load_lds wave-instruction.
// For a 32-k step tk, global plane offset = tk*2048 + pb*512 (pb in [0,4)).
// NOTE: global_load_lds needs a PER-LANE global address (lane*16B) and a
// wave-uniform LDS base.

// ---------------------------------------------------------------------------
// P0: merged prep. blocks [0,3072): transpose x -> Xtp packed.
//     blocks [3072,5376): pack A -> Abp. block 5376: cvt W/b -> Wb.
// dtype sniff (k_detect logic) folded in: each wave recomputes the ballot
// from the same 64 words of x -> identical flag, no separate dispatch.
// ---------------------------------------------------------------------------
__global__ __launch_bounds__(256) void k_prep(const void* __restrict__ xin,
                                              const void* __restrict__ Ain,
                                              const void* __restrict__ W0,
                                              const void* __restrict__ b0,
                                              const void* __restrict__ W1,
                                              const void* __restrict__ b1,
                                              unsigned short* __restrict__ xtp,
                                              unsigned short* __restrict__ Abp,
                                              unsigned short* __restrict__ wb) {
  __shared__ __align__(16) unsigned short sh[64 * 65];  // 4160: fits both tiles
  const int t = threadIdx.x;
  const int bid = blockIdx.x;
  // inline dtype sniff (HW-validated heuristic): fp32 exponents cluster >150
  int fp;
  {
    uint32_t u = ((const uint32_t*)xin)[(t & 63) * 97 + 1];
    int e = (u >> 7) & 0xFF;
    unsigned long long m = __ballot(e > 150);
    fp = (__popcll(m) > 6) ? 1 : 0;
  }

  if (bid < 3072) {
    // ---- transpose: x (3072 w x 4096 m) -> Xtp packed (rows m, k=w) ----
    const int w0 = (bid % 48) * 64;
    const int m0 = (bid / 48) * 64;
    if (fp) {
      const float* xf = (const float*)xin;
#pragma unroll
      for (int rep = 0; rep < 4; ++rep) {
        int vi = t + rep * 256;
        int r = vi >> 4;                // w-local
        int c4 = (vi & 15) * 4;        // m-local
        f32x4 v = *(const f32x4*)(xf + (uint64_t)(w0 + r) * 4096 + m0 + c4);
#pragma unroll
        for (int u = 0; u < 4; ++u) sh[(c4 + u) * 65 + r] = f2bf(v[u]);
      }
    } else {
      const unsigned short* xb = (const unsigned short*)xin;
#pragma unroll
      for (int rep = 0; rep < 2; ++rep) {
        int vi = t + rep * 256;
        int r = vi >> 3;
        int c8 = (vi & 7) * 8;
        u16x8 v = *(const u16x8*)(xb + (uint64_t)(w0 + r) * 4096 + m0 + c8);
#pragma unroll
        for (int u = 0; u < 8; ++u) sh[(c8 + u) * 65 + r] = v[u];
      }
    }
    __syncthreads();
    unsigned short* dst = xtp + ((uint64_t)(m0 >> 6) * 48 + (w0 >> 6)) * 4096;
#pragma unroll
    for (int rep = 0; rep < 2; ++rep) {
      int vi = t + rep * 256;           // [0,512)
      int kb = vi >> 6, r = vi & 63;
      u16x8 v;
#pragma unroll
      for (int u = 0; u < 8; ++u) v[u] = sh[r * 65 + kb * 8 + u];
      *(u16x8*)(dst + kb * 512 + r * 8) = v;
    }
  } else if (bid < 5376) {
    // ---- pack A (3072x3072) -> Abp; LDS bounce planes padded to 520 ----
    const int b2 = bid - 3072;
    const int kt = b2 % 48, rt = b2 / 48;
    if (fp) {
      const float* Af = (const float*)Ain;
#pragma unroll
      for (int rep = 0; rep < 4; ++rep) {
        int vi = t + rep * 256;
        int r = vi >> 4;
        int c4 = (vi & 15) * 4;
        f32x4 v = *(const f32x4*)(Af + (uint64_t)(rt * 64 + r) * 3072 + kt * 64 + c4);
        int kb = c4 >> 3, e = c4 & 7;
#pragma unroll
        for (int u = 0; u < 4; ++u) sh[kb * 520 + r * 8 + e + u] = f2bf(v[u]);
      }
    } else {
      const unsigned short* Ab16 = (const unsigned short*)Ain;
#pragma unroll
      for (int rep = 0; rep < 2; ++rep) {
        int vi = t + rep * 256;
        int r = vi >> 3;
        int c8 = (vi & 7) * 8;
        u16x8 v = *(const u16x8*)(Ab16 + (uint64_t)(rt * 64 + r) * 3072 + kt * 64 + c8);
#pragma unroll
        for (int u = 0; u < 8; ++u) sh[(c8 >> 3) * 520 + r * 8 + u] = v[u];
      }
    }
    __syncthreads();
    unsigned short* dst = Abp + ((uint64_t)rt * 48 + kt) * 4096;
#pragma unroll
    for (int rep = 0; rep < 2; ++rep) {
      int vi = t + rep * 256;
      int kb = vi >> 6, r = vi & 63;
      u16x8 v;
#pragma unroll
      for (int u = 0; u < 8; ++u) v[u] = sh[kb * 520 + r * 8 + u];
      *(u16x8*)(dst + kb * 512 + r * 8) = v;
    }
  } else {
    // ---- W0,b0,W1,b1 -> contiguous bf16 block wb[16640] ----
    for (int i = t; i < 16640; i += 256) {
      const void* src; int off;
      if (i < 8192)        { src = W0; off = i; }
      else if (i < 8320)   { src = b0; off = i - 8192; }
      else if (i < 16512)  { src = W1; off = i - 8320; }
      else                 { src = b1; off = i - 16512; }
      wb[i] = fp ? f2bf(((const float*)src)[off]) : ((const unsigned short*)src)[off];
    }
  }
}

// ---------------------------------------------------------------------------
// Fused NT GEMM + 1x1 conv + GLU — phase-interleaved, counted-vmcnt schedule,
// register-fragment SOFTWARE PIPELINE (reads one phase ahead of their MFMA).
// 512 threads = 8 waves (2 Mv x 4 Nm). BK=32 K-tiles, 4-deep LDS ring buffer,
// prefetch 3 tiles ahead; per-tile wait leaves 2 tiles in flight (never
// vmcnt(0) in steady state). MFMA never waits on its own ds_reads: frags for
// phase p+1 are issued before phase p's MFMA cluster.
// ---------------------------------------------------------------------------
template <int BM, int KTOT>
__global__ __launch_bounds__(512, 2) void k_gemm_glu3(
    const unsigned short* __restrict__ Am,
    const unsigned short* __restrict__ Bm,
    const unsigned short* __restrict__ W,
    const unsigned short* __restrict__ bias,
    unsigned short* __restrict__ H,
    int Vtot) {
  constexpr int BN  = 256;                 // m-tile (fixed)
  constexpr int IF  = BM / 32;             // A frags per wave (wave M = BM/2)
  constexpr int NPH = (IF > 4) ? 2 : 1;    // phases per K-tile
  constexpr int IPH = IF / NPH;            // A frags per phase
  constexpr int APL = (BM / 64) * 4;       // A planes per 32k K-tile
  constexpr int P   = APL + 16;            // total planes per K-tile (B=16)
  constexpr int QF  = P / 8;               // full staging rounds per wave
  constexpr int QR  = P - QF * 8;          // waves with one extra plane
  constexpr int PPW = QF + (QR ? 1 : 0);
  constexpr int BUFS = P * 512;            // ushorts per ring slot
  constexpr int NT  = KTOT / 32;           // K-tiles
  constexpr int Kt  = KTOT / 64;           // packed 64k tiles in K
  constexpr int NRB = BM / 16;             // epilogue 16-row blocks
  constexpr int EPL = BM * 264;            // epilogue G staging (ushorts)
  constexpr int SME = (4 * BUFS > EPL) ? 4 * BUFS : EPL;

  __shared__ __align__(16) unsigned short smem[SME];

  const int t    = threadIdx.x;
  const int lane = t & 63;
  const int wid  = t >> 6;
  const int wV   = wid >> 2;   // 0..1 : v-half of tile
  const int wM   = wid & 3;    // 0..3 : 64-wide m-slice
  const int fr   = lane & 15;
  const int q4   = lane >> 4;
  const int v0   = blockIdx.x * BM;
  const int m0   = blockIdx.y * BN;
  const int art0 = v0 >> 6;
  const int brt0 = m0 >> 6;

  // ---- staging descriptors: plane pi = wid + 8q, round-robin over waves ----
  const int myq = QF + ((QR && wid < QR) ? 1 : 0);
  const unsigned short* srcb[PPW];
  int ldso[PPW];
#pragma unroll
  for (int q = 0; q < PPW; ++q) {
    int pi = wid + 8 * q;
    if (pi >= P) pi = P - 1;  // inert (guarded by q<myq at issue)
    const int isA = pi < APL;
    const int rtl = (isA ? pi : pi - APL) >> 2;
    const int pb  = pi & 3;
    const unsigned short* base =
        isA ? (Am + (uint64_t)(art0 + rtl) * Kt * 4096)
            : (Bm + (uint64_t)(brt0 + rtl) * Kt * 4096);
    srcb[q] = base + pb * 512 + lane * 8;  // per-lane 16B chunk
    ldso[q] = pi * 512;                    // wave-uniform LDS plane
  }

  // ---- fragment LDS offsets (within ring slot) ----
  int aoff[IF], boff[4];
#pragma unroll
  for (int i = 0; i < IF; ++i) {
    const int row = wV * (BM / 2) + i * 16 + fr;
    aoff[i] = ((row >> 6) * 4 + q4) * 512 + (row & 63) * 8;
  }
#pragma unroll
  for (int j = 0; j < 4; ++j)
    boff[j] = (APL + wM * 4 + q4) * 512 + (j * 16 + fr) * 8;

  f32x4 acc[IF][4] = {};

  // ---- prologue: stage K-tiles 0..2 into ring slots 0..2 ----
#pragma unroll
  for (int pt = 0; pt < 3; ++pt)
#pragma unroll
    for (int q = 0; q < PPW; ++q)
      if (q < myq)
        load_lds16(srcb[q] + pt * 2048, smem + pt * BUFS + ldso[q]);
  if (QR && wid < QR) { vmw<2 * (QF + 1)>(); } else { vmw<2 * QF>(); }  // tile 0 landed
  SBAR();

  // pipeline prime: tile 0 frags (B + phase-0 A) into registers
  s16x8 bcur[4], a0[IPH];
#pragma unroll
  for (int j = 0; j < 4; ++j) bcur[j] = *(const s16x8*)(smem + boff[j]);
#pragma unroll
  for (int i = 0; i < IPH; ++i) a0[i] = *(const s16x8*)(smem + aoff[i]);
  s16x8 a1[IPH];

  // ---- main loop (last tile peeled): compute tt, prefetch tt+3,
  //      read tile tt+1 frags before tile tt's final MFMA cluster ----
#pragma unroll 2
  for (int tt = 0; tt < NT - 1; ++tt) {
    const unsigned short* buf  = smem + (tt & 3) * BUFS;
    const unsigned short* bufn = smem + ((tt + 1) & 3) * BUFS;
    unsigned short* pdst = smem + ((tt + 3) & 3) * BUFS;
    if constexpr (NPH == 2) {
      // --- phase A: read tt.ph1 A frags; MFMA tt.ph0 (frags pre-loaded) ---
#pragma unroll
      for (int i = 0; i < IPH; ++i)
        a1[i] = *(const s16x8*)(buf + aoff[IPH + i]);
      if (tt + 3 < NT) {
#pragma unroll
        for (int q = 0; q < PPW; ++q)
          if ((q & 1) == 0 && q < myq)
            load_lds16(srcb[q] + (uint64_t)(tt + 3) * 2048, pdst + ldso[q]);
      }
      SBAR();
      __builtin_amdgcn_s_setprio(1);
#pragma unroll
      for (int i = 0; i < IPH; ++i)
#pragma unroll
        for (int j = 0; j < 4; ++j)
          acc[i][j] = __builtin_amdgcn_mfma_f32_16x16x32_bf16(a0[i], bcur[j],
                                                              acc[i][j], 0, 0, 0);
      __builtin_amdgcn_s_setprio(0);
      SBAR();
      // --- phase B: land tt+1, read its B + ph0 A frags; MFMA tt.ph1 ---
      if (tt + 3 < NT) {
#pragma unroll
        for (int q = 0; q < PPW; ++q)
          if ((q & 1) == 1 && q < myq)
            load_lds16(srcb[q] + (uint64_t)(tt + 3) * 2048, pdst + ldso[q]);
        if (QR && wid < QR) { vmw<2 * (QF + 1)>(); } else { vmw<2 * QF>(); }
      } else if (tt + 2 < NT) {
        if (QR && wid < QR) { vmw<QF + 1>(); } else { vmw<QF>(); }
      } else {
        vmw<0>();
      }
      SBAR();
      s16x8 bnxt[4], a0n[IPH];
#pragma unroll
      for (int j = 0; j < 4; ++j) bnxt[j] = *(const s16x8*)(bufn + boff[j]);
#pragma unroll
      for (int i = 0; i < IPH; ++i) a0n[i] = *(const s16x8*)(bufn + aoff[i]);
      __builtin_amdgcn_s_setprio(1);
#pragma unroll
      for (int i = 0; i < IPH; ++i)
#pragma unroll
        for (int j = 0; j < 4; ++j)
          acc[IPH + i][j] = __builtin_amdgcn_mfma_f32_16x16x32_bf16(
              a1[i], bcur[j], acc[IPH + i][j], 0, 0, 0);
      __builtin_amdgcn_s_setprio(0);
      SBAR();
#pragma unroll
      for (int j = 0; j < 4; ++j) bcur[j] = bnxt[j];
#pragma unroll
      for (int i = 0; i < IPH; ++i) a0[i] = a0n[i];
    } else {
      // --- single phase: land tt+1, read its frags; MFMA tt ---
      if (tt + 3 < NT) {
#pragma unroll
        for (int q = 0; q < PPW; ++q)
          if (q < myq)
            load_lds16(srcb[q] + (uint64_t)(tt + 3) * 2048, pdst + ldso[q]);
        if (QR && wid < QR) { vmw<2 * (QF + 1)>(); } else { vmw<2 * QF>(); }
      } else if (tt + 2 < NT) {
        if (QR && wid < QR) { vmw<QF + 1>(); } else { vmw<QF>(); }
      } else {
        vmw<0>();
      }
      SBAR();
      s16x8 bnxt[4], a0n[IPH];
#pragma unroll
      for (int j = 0; j < 4; ++j) bnxt[j] = *(const s16x8*)(bufn + boff[j]);
#pragma unroll
      for (int i = 0; i < IPH; ++i) a0n[i] = *(const s16x8*)(bufn + aoff[i]);
      __builtin_amdgcn_s_setprio(1);
#pragma unroll
      for (int i = 0; i < IPH; ++i)
#pragma unroll
        for (int j = 0; j < 4; ++j)
          acc[i][j] = __builtin_amdgcn_mfma_f32_16x16x32_bf16(a0[i], bcur[j],
                                                              acc[i][j], 0, 0, 0);
      __builtin_amdgcn_s_setprio(0);
      SBAR();
#pragma unroll
      for (int j = 0; j < 4; ++j) bcur[j] = bnxt[j];
#pragma unroll
      for (int i = 0; i < IPH; ++i) a0[i] = a0n[i];
    }
  }
  // ---- peeled last tile (frags already in registers; no stage/waits) ----
  if constexpr (NPH == 2) {
    const unsigned short* buf = smem + ((NT - 1) & 3) * BUFS;
#pragma unroll
    for (int i = 0; i < IPH; ++i)
      a1[i] = *(const s16x8*)(buf + aoff[IPH + i]);
#pragma unroll
    for (int i = 0; i < IPH; ++i)
#pragma unroll
      for (int j = 0; j < 4; ++j)
        acc[i][j] = __builtin_amdgcn_mfma_f32_16x16x32_bf16(a0[i], bcur[j],
                                                            acc[i][j], 0, 0, 0);
#pragma unroll
    for (int i = 0; i < IPH; ++i)
#pragma unroll
      for (int j = 0; j < 4; ++j)
        acc[IPH + i][j] = __builtin_amdgcn_mfma_f32_16x16x32_bf16(
            a1[i], bcur[j], acc[IPH + i][j], 0, 0, 0);
  } else {
#pragma unroll
    for (int i = 0; i < IPH; ++i)
#pragma unroll
      for (int j = 0; j < 4; ++j)
        acc[i][j] = __builtin_amdgcn_mfma_f32_16x16x32_bf16(a0[i], bcur[j],
                                                            acc[i][j], 0, 0, 0);
  }

  // ---- epilogue: G-tile -> LDS (stride 264), conv + GLU, packed H write ----
  __syncthreads();
  {
    const int rr = q4 * 4;
#pragma unroll
    for (int i = 0; i < IF; ++i)
#pragma unroll
      for (int j = 0; j < 4; ++j) {
        const int col = wM * 64 + j * 16 + fr;
#pragma unroll
        for (int r = 0; r < 4; ++r) {
          const int row = wV * (BM / 2) + i * 16 + rr + r;
          smem[row * 264 + col] = f2bf(acc[i][j][r]);
        }
      }
  }
  __syncthreads();

  s16x8 wf[2][8];
#pragma unroll
  for (int ksi = 0; ksi < 2; ++ksi)
#pragma unroll
    for (int j = 0; j < 8; ++j)
      wf[ksi][j] = *(const s16x8*)(W + (j * 16 + fr) * 64 + ksi * 32 + q4 * 8);
  float bj[8];
#pragma unroll
  for (int j = 0; j < 8; ++j) bj[j] = bf2f(bias[j * 16 + fr]);

  const int Vt = Vtot >> 6;
#pragma unroll
  for (int rep = 0; rep < (NRB + 7) / 8; ++rep) {
    const int rb = rep * 8 + wid;
    if (rb < NRB) {
#pragma unroll
      for (int bb = 0; bb < 4; ++bb) {
        f32x4 acc2[8] = {};
#pragma unroll
        for (int ksi = 0; ksi < 2; ++ksi) {
          s16x8 af = *(const s16x8*)(smem + (rb * 16 + fr) * 264 + bb * 64 +
                                     ksi * 32 + q4 * 8);
#pragma unroll
          for (int j = 0; j < 8; ++j)
            acc2[j] = __builtin_amdgcn_mfma_f32_16x16x32_bf16(af, wf[ksi][j],
                                                              acc2[j], 0, 0, 0);
        }
        const int v = v0 + rb * 16 + q4 * 4;
#pragma unroll
        for (int j = 0; j < 4; ++j) {
          u16x4 pk;
#pragma unroll
          for (int r = 0; r < 4; ++r) {
            float lhs = acc2[j][r] + bj[j];
            float rhs = acc2[j + 4][r] + bj[j + 4];
            float sg = 1.0f / (1.0f + __expf(-rhs));
            pk[r] = f2bf(lhs * sg);
          }
          const int o = j * 16 + fr;
          const int hrow = m0 + bb * 64 + o;
          *(u16x4*)(H + ((uint64_t)(hrow >> 6) * Vt + (v >> 6)) * 4096 +
                    ((v >> 3) & 7) * 512 + (hrow & 63) * 8 + (v & 7)) = pk;
        }
      }
    }
  }
}

// ---------------------------------------------------------------------------
// out[n][b][j] = max(H1p[b*64+j][1024+n], H2p[b*64+j][n]); packed H reads.
// ---------------------------------------------------------------------------
__global__ __launch_bounds__(256) void k_maxout(const unsigned short* __restrict__ H1,
                                                const unsigned short* __restrict__ H2,
                                                float* __restrict__ out) {
  __shared__ __align__(16) float tile[64 * 65];  // [j][n]
  const int t = threadIdx.x;
  const int b = blockIdx.y;
  const int n0 = blockIdx.x * 64;
  {
    int j = t >> 2, p = t & 3;
    int c1 = 1024 + n0 + p * 16;   // H1 col (Kt 48)
    int c2 = n0 + p * 16;          // H2 col (Kt 16)
    const unsigned short* h1p =
        H1 + ((uint64_t)b * 48 + (c1 >> 6)) * 4096 + ((c1 >> 3) & 7) * 512 + j * 8;
    const unsigned short* h2p =
        H2 + ((uint64_t)b * 16 + (c2 >> 6)) * 4096 + ((c2 >> 3) & 7) * 512 + j * 8;
    u16x8 a0 = *(const u16x8*)(h1p);
    u16x8 a1 = *(const u16x8*)(h1p + 512);
    u16x8 c0 = *(const u16x8*)(h2p);
    u16x8 c1v = *(const u16x8*)(h2p + 512);
#pragma unroll
    for (int u = 0; u < 8; ++u) {
      tile[j * 65 + p * 16 + u] = fmaxf(bf2f(a0[u]), bf2f(c0[u]));
      tile[j * 65 + p * 16 + 8 + u] = fmaxf(bf2f(a1[u]), bf2f(c1v[u]));
    }
  }
  __syncthreads();
  {
    int n = t >> 2, jb = (t & 3) * 16;
    float* op = out + (uint64_t)(n0 + n) * 4096 + b * 64 + jb;
#pragma unroll
    for (int q = 0; q < 4; ++q) {
      f32x4 o;
#pragma unroll
      for (int u = 0; u < 4; ++u) o[u] = tile[(jb + q * 4 + u) * 65 + n];
      *(f32x4*)(op + q * 4) = o;
    }
  }
}

// ---------------------------------------------------------------------------
extern "C" void kernel_launch(void* const* d_in, const int* in_sizes, int n_in,
                              void* d_out, int out_size, void* d_ws, size_t ws_size,
                              hipStream_t stream) {
  (void)in_sizes; (void)n_in; (void)out_size; (void)ws_size;
  const void* x  = d_in[0];  // [3072][64][64]
  const void* A  = d_in[1];  // [3072][3072]
  const void* W0 = d_in[2];  // [128][64]
  const void* b0 = d_in[3];  // [128]
  const void* W1 = d_in[4];  // [128][64]
  const void* b1 = d_in[5];  // [128]
  float* out = (float*)d_out;  // [1024][64][64] fp32

  char* ws = (char*)d_ws;
  unsigned short* Xtp = (unsigned short*)(ws + 0);         // 25165824 B (dead after K1f)
  unsigned short* H2p = (unsigned short*)(ws + 0);         // 8388608 B (overlay)
  unsigned short* Abp = (unsigned short*)(ws + 25165824);  // 18874368 B
  unsigned short* Wb  = (unsigned short*)(ws + 44040192);  // 33280 B
  unsigned short* H1p = (unsigned short*)(ws + 44105728);  // 25165824 B -> end 69271552
  int* flag = (int*)(ws + 69271552);
  (void)flag;

  // P0: transpose (3072 blocks) + packA (2304) + cvtW (1), detect folded in
  k_prep<<<5377, 256, 0, stream>>>(x, A, W0, b0, W1, b1, Xtp, Abp, Wb);
  // K1f: H1 = GLU(W0.(A.Xt^T)+b0), v covers 3072. 192x256 tiles -> 16x16 =
  // 256 blocks = exactly 1 per CU (full chip).
  k_gemm_glu3<192, 3072><<<dim3(16, 16), 512, 0, stream>>>(
      Abp, Xtp, Wb, Wb + 8192, H1p, 3072);
  // K3f: H2 = GLU(W1.(A[rows 1024+].H1^T)+b1), middle third (A row-tile
  // offset 16). 64x256 tiles -> 16x16 = 256 blocks = full chip.
  k_gemm_glu3<64, 3072><<<dim3(16, 16), 512, 0, stream>>>(
      Abp + (uint64_t)16 * 48 * 4096, H1p, Wb + 8320, Wb + 16512, H2p, 1024);
  k_maxout<<<dim3(16, 64), 256, 0, stream>>>(H1p, H2p, out);
}

// Round 4
// 261.504 us; speedup vs baseline: 1.0712x; 1.0712x over previous
//
#include <hip/hip_runtime.h>
#include <hip/hip_bf16.h>
#include <stdint.h>

typedef __attribute__((ext_vector_type(8))) short s16x8;           // MFMA A/B frag: 8 bf16
typedef __attribute__((ext_vector_type(4))) float f32x4;           // MFMA C/D frag / fp32 vec4
typedef __attribute__((ext_vector_type(8))) unsigned short u16x8;  // 16B vector
typedef __attribute__((ext_vector_type(4))) unsigned short u16x4;  // 8B vector

__device__ __forceinline__ float bf2f(unsigned short u) {
  union { uint32_t u; float f; } v; v.u = ((uint32_t)u) << 16; return v.f;
}
__device__ __forceinline__ unsigned short f2bf(float f) {
  union { float f; uint32_t u; } v; v.f = f;
  uint32_t u = v.u;
  return (unsigned short)((u + 0x7fffu + ((u >> 16) & 1u)) >> 16);  // RNE
}
__device__ __forceinline__ void load_lds16(const void* g, void* l) {
  __builtin_amdgcn_global_load_lds(
      (const __attribute__((address_space(1))) void*)g,
      (__attribute__((address_space(3))) void*)l, 16, 0, 0);
}

template <int N>
__device__ __forceinline__ void vmw() {
  if constexpr (N == 0) asm volatile("s_waitcnt vmcnt(0)" ::: "memory");
  else if constexpr (N == 1) asm volatile("s_waitcnt vmcnt(1)" ::: "memory");
  else if constexpr (N == 2) asm volatile("s_waitcnt vmcnt(2)" ::: "memory");
  else if constexpr (N == 3) asm volatile("s_waitcnt vmcnt(3)" ::: "memory");
  else if constexpr (N == 4) asm volatile("s_waitcnt vmcnt(4)" ::: "memory");
  else if constexpr (N == 5) asm volatile("s_waitcnt vmcnt(5)" ::: "memory");
  else if constexpr (N == 6) asm volatile("s_waitcnt vmcnt(6)" ::: "memory");
  else if constexpr (N == 7) asm volatile("s_waitcnt vmcnt(7)" ::: "memory");
  else asm volatile("s_waitcnt vmcnt(8)" ::: "memory");
}
#define SBAR() asm volatile("s_barrier" ::: "memory")

// PACKED LAYOUT: matrix [R][Kd] -> tiles 64r x 64k. Tile (rt,kt) at ushort
// offset (rt*(Kd/64)+kt)*4096; within tile: plane kb (k=kb*8+e) at kb*512,
// row r at r*8, elem e. Plane = 1 KB = one global_load_lds wave-instruction.
// For a 32-k step tk, global plane offset = tk*2048 + pb*512 (pb in [0,4)).
// NOTE: global_load_lds needs a PER-LANE global address (lane*16B) and a
// wave-uniform LDS base.

// ---------------------------------------------------------------------------
// P0: merged prep. blocks [0,3072): transpose x -> Xtp packed.
//     blocks [3072,5376): pack A -> Abp. block 5376: cvt W/b -> Wb.
// dtype sniff folded in: each wave recomputes the ballot from the same 64
// words of x -> identical flag, no separate dispatch.
// ---------------------------------------------------------------------------
__global__ __launch_bounds__(256) void k_prep(const void* __restrict__ xin,
                                              const void* __restrict__ Ain,
                                              const void* __restrict__ W0,
                                              const void* __restrict__ b0,
                                              const void* __restrict__ W1,
                                              const void* __restrict__ b1,
                                              unsigned short* __restrict__ xtp,
                                              unsigned short* __restrict__ Abp,
                                              unsigned short* __restrict__ wb) {
  __shared__ __align__(16) unsigned short sh[64 * 65];  // 4160: fits both tiles
  const int t = threadIdx.x;
  const int bid = blockIdx.x;
  // inline dtype sniff (HW-validated heuristic): fp32 exponents cluster >150
  int fp;
  {
    uint32_t u = ((const uint32_t*)xin)[(t & 63) * 97 + 1];
    int e = (u >> 7) & 0xFF;
    unsigned long long m = __ballot(e > 150);
    fp = (__popcll(m) > 6) ? 1 : 0;
  }

  if (bid < 3072) {
    // ---- transpose: x (3072 w x 4096 m) -> Xtp packed (rows m, k=w) ----
    const int w0 = (bid % 48) * 64;
    const int m0 = (bid / 48) * 64;
    if (fp) {
      const float* xf = (const float*)xin;
#pragma unroll
      for (int rep = 0; rep < 4; ++rep) {
        int vi = t + rep * 256;
        int r = vi >> 4;                // w-local
        int c4 = (vi & 15) * 4;        // m-local
        f32x4 v = *(const f32x4*)(xf + (uint64_t)(w0 + r) * 4096 + m0 + c4);
#pragma unroll
        for (int u = 0; u < 4; ++u) sh[(c4 + u) * 65 + r] = f2bf(v[u]);
      }
    } else {
      const unsigned short* xb = (const unsigned short*)xin;
#pragma unroll
      for (int rep = 0; rep < 2; ++rep) {
        int vi = t + rep * 256;
        int r = vi >> 3;
        int c8 = (vi & 7) * 8;
        u16x8 v = *(const u16x8*)(xb + (uint64_t)(w0 + r) * 4096 + m0 + c8);
#pragma unroll
        for (int u = 0; u < 8; ++u) sh[(c8 + u) * 65 + r] = v[u];
      }
    }
    __syncthreads();
    unsigned short* dst = xtp + ((uint64_t)(m0 >> 6) * 48 + (w0 >> 6)) * 4096;
#pragma unroll
    for (int rep = 0; rep < 2; ++rep) {
      int vi = t + rep * 256;           // [0,512)
      int kb = vi >> 6, r = vi & 63;
      u16x8 v;
#pragma unroll
      for (int u = 0; u < 8; ++u) v[u] = sh[r * 65 + kb * 8 + u];
      *(u16x8*)(dst + kb * 512 + r * 8) = v;
    }
  } else if (bid < 5376) {
    // ---- pack A (3072x3072) -> Abp; LDS bounce planes padded to 520 ----
    const int b2 = bid - 3072;
    const int kt = b2 % 48, rt = b2 / 48;
    if (fp) {
      const float* Af = (const float*)Ain;
#pragma unroll
      for (int rep = 0; rep < 4; ++rep) {
        int vi = t + rep * 256;
        int r = vi >> 4;
        int c4 = (vi & 15) * 4;
        f32x4 v = *(const f32x4*)(Af + (uint64_t)(rt * 64 + r) * 3072 + kt * 64 + c4);
        int kb = c4 >> 3, e = c4 & 7;
#pragma unroll
        for (int u = 0; u < 4; ++u) sh[kb * 520 + r * 8 + e + u] = f2bf(v[u]);
      }
    } else {
      const unsigned short* Ab16 = (const unsigned short*)Ain;
#pragma unroll
      for (int rep = 0; rep < 2; ++rep) {
        int vi = t + rep * 256;
        int r = vi >> 3;
        int c8 = (vi & 7) * 8;
        u16x8 v = *(const u16x8*)(Ab16 + (uint64_t)(rt * 64 + r) * 3072 + kt * 64 + c8);
#pragma unroll
        for (int u = 0; u < 8; ++u) sh[(c8 >> 3) * 520 + r * 8 + u] = v[u];
      }
    }
    __syncthreads();
    unsigned short* dst = Abp + ((uint64_t)rt * 48 + kt) * 4096;
#pragma unroll
    for (int rep = 0; rep < 2; ++rep) {
      int vi = t + rep * 256;
      int kb = vi >> 6, r = vi & 63;
      u16x8 v;
#pragma unroll
      for (int u = 0; u < 8; ++u) v[u] = sh[kb * 520 + r * 8 + u];
      *(u16x8*)(dst + kb * 512 + r * 8) = v;
    }
  } else {
    // ---- W0,b0,W1,b1 -> contiguous bf16 block wb[16640] ----
    for (int i = t; i < 16640; i += 256) {
      const void* src; int off;
      if (i < 8192)        { src = W0; off = i; }
      else if (i < 8320)   { src = b0; off = i - 8192; }
      else if (i < 16512)  { src = W1; off = i - 8320; }
      else                 { src = b1; off = i - 16512; }
      wb[i] = fp ? f2bf(((const float*)src)[off]) : ((const unsigned short*)src)[off];
    }
  }
}

// ---------------------------------------------------------------------------
// Fused NT GEMM + 1x1 conv + GLU — ONE barrier per K-tile, counted vmcnt.
// 512 threads = 8 waves (2 Mv x 4 Nm). BK=32 K-tiles, 4-deep LDS ring,
// prefetch 3 tiles ahead. Per tile: {ds_read all frags || issue stage
// tt+3 || setprio(1) MFMA setprio(0) || counted vmw || s_barrier}.
// Single-barrier legality: each wave's frag reads are consumed by its MFMAs
// (lgkmcnt) before it reaches the barrier; the barrier then both publishes
// tile tt+1 (vmw'd) and separates last-reads of a slot from its re-staging
// 3 tiles later. FUSEMAX: epilogue reads matching packed H1 col (1024+v),
// maxes with the in-register GLU value, writes fp32 out (maxout dispatch
// and the H2 buffer are eliminated).
// ---------------------------------------------------------------------------
template <int BM, int KTOT, bool FUSEMAX>
__global__ __launch_bounds__(512, 2) void k_gemm_glu4(
    const unsigned short* __restrict__ Am,
    const unsigned short* __restrict__ Bm,
    const unsigned short* __restrict__ W,
    const unsigned short* __restrict__ bias,
    unsigned short* __restrict__ H,          // !FUSEMAX: packed H out
    const unsigned short* __restrict__ Hprev, // FUSEMAX: packed H1 (Vt=48)
    float* __restrict__ outp,                 // FUSEMAX: fp32 out
    int Vtot) {
  constexpr int BN  = 256;                 // m-tile (fixed)
  constexpr int IF  = BM / 32;             // A frags per wave (wave M = BM/2)
  constexpr int APL = (BM / 64) * 4;       // A planes per 32k K-tile
  constexpr int P   = APL + 16;            // total planes per K-tile (B=16)
  constexpr int QF  = P / 8;               // full staging rounds per wave
  constexpr int QR  = P - QF * 8;          // waves with one extra plane
  constexpr int PPW = QF + (QR ? 1 : 0);
  constexpr int BUFS = P * 512;            // ushorts per ring slot
  constexpr int NT  = KTOT / 32;           // K-tiles
  constexpr int Kt  = KTOT / 64;           // packed 64k tiles in K
  constexpr int NRB = BM / 16;             // epilogue 16-row blocks
  constexpr int EPL = BM * 264;            // epilogue G staging (ushorts)
  constexpr int SME = (4 * BUFS > EPL) ? 4 * BUFS : EPL;

  __shared__ __align__(16) unsigned short smem[SME];

  const int t    = threadIdx.x;
  const int lane = t & 63;
  const int wid  = t >> 6;
  const int wV   = wid >> 2;   // 0..1 : v-half of tile
  const int wM   = wid & 3;    // 0..3 : 64-wide m-slice
  const int fr   = lane & 15;
  const int q4   = lane >> 4;
  const int v0   = blockIdx.x * BM;
  const int m0   = blockIdx.y * BN;
  const int art0 = v0 >> 6;
  const int brt0 = m0 >> 6;

  // ---- staging descriptors: plane pi = wid + 8q, round-robin over waves ----
  const int myq = QF + ((QR && wid < QR) ? 1 : 0);
  const unsigned short* srcb[PPW];
  int ldso[PPW];
#pragma unroll
  for (int q = 0; q < PPW; ++q) {
    int pi = wid + 8 * q;
    if (pi >= P) pi = P - 1;  // inert (guarded by q<myq at issue)
    const int isA = pi < APL;
    const int rtl = (isA ? pi : pi - APL) >> 2;
    const int pb  = pi & 3;
    const unsigned short* base =
        isA ? (Am + (uint64_t)(art0 + rtl) * Kt * 4096)
            : (Bm + (uint64_t)(brt0 + rtl) * Kt * 4096);
    srcb[q] = base + pb * 512 + lane * 8;  // per-lane 16B chunk
    ldso[q] = pi * 512;                    // wave-uniform LDS plane
  }

  // ---- fragment LDS offsets (within ring slot) ----
  int aoff[IF], boff[4];
#pragma unroll
  for (int i = 0; i < IF; ++i) {
    const int row = wV * (BM / 2) + i * 16 + fr;
    aoff[i] = ((row >> 6) * 4 + q4) * 512 + (row & 63) * 8;
  }
#pragma unroll
  for (int j = 0; j < 4; ++j)
    boff[j] = (APL + wM * 4 + q4) * 512 + (j * 16 + fr) * 8;

  f32x4 acc[IF][4] = {};

  // ---- prologue: stage K-tiles 0..2 into ring slots 0..2 ----
#pragma unroll
  for (int pt = 0; pt < 3; ++pt)
#pragma unroll
    for (int q = 0; q < PPW; ++q)
      if (q < myq)
        load_lds16(srcb[q] + pt * 2048, smem + pt * BUFS + ldso[q]);
  if (QR && wid < QR) { vmw<2 * (QF + 1)>(); } else { vmw<2 * QF>(); }  // tile 0 landed
  SBAR();

  // ---- main loop: ONE barrier per K-tile ----
#pragma unroll 4
  for (int tt = 0; tt < NT; ++tt) {
    const unsigned short* buf = smem + (tt & 3) * BUFS;
    s16x8 bfr[4], afr[IF];
#pragma unroll
    for (int j = 0; j < 4; ++j) bfr[j] = *(const s16x8*)(buf + boff[j]);
#pragma unroll
    for (int i = 0; i < IF; ++i) afr[i] = *(const s16x8*)(buf + aoff[i]);
    if (tt + 3 < NT) {
      unsigned short* pdst = smem + ((tt + 3) & 3) * BUFS;
#pragma unroll
      for (int q = 0; q < PPW; ++q)
        if (q < myq)
          load_lds16(srcb[q] + (uint64_t)(tt + 3) * 2048, pdst + ldso[q]);
    }
    __builtin_amdgcn_s_setprio(1);
#pragma unroll
    for (int i = 0; i < IF; ++i)
#pragma unroll
      for (int j = 0; j < 4; ++j)
        acc[i][j] = __builtin_amdgcn_mfma_f32_16x16x32_bf16(afr[i], bfr[j],
                                                            acc[i][j], 0, 0, 0);
    __builtin_amdgcn_s_setprio(0);
    if (tt + 3 < NT) {        // leave tiles tt+2, tt+3 in flight
      if (QR && wid < QR) { vmw<2 * (QF + 1)>(); } else { vmw<2 * QF>(); }
    } else if (tt + 2 < NT) { // leave tile tt+2 in flight
      if (QR && wid < QR) { vmw<QF + 1>(); } else { vmw<QF>(); }
    } else {
      vmw<0>();
    }
    SBAR();
  }

  // ---- epilogue: G-tile -> LDS (stride 264), conv + GLU ----
  __syncthreads();
  {
    const int rr = q4 * 4;
#pragma unroll
    for (int i = 0; i < IF; ++i)
#pragma unroll
      for (int j = 0; j < 4; ++j) {
        const int col = wM * 64 + j * 16 + fr;
#pragma unroll
        for (int r = 0; r < 4; ++r) {
          const int row = wV * (BM / 2) + i * 16 + rr + r;
          smem[row * 264 + col] = f2bf(acc[i][j][r]);
        }
      }
  }
  __syncthreads();

  s16x8 wf[2][8];
#pragma unroll
  for (int ksi = 0; ksi < 2; ++ksi)
#pragma unroll
    for (int j = 0; j < 8; ++j)
      wf[ksi][j] = *(const s16x8*)(W + (j * 16 + fr) * 64 + ksi * 32 + q4 * 8);
  float bj[8];
#pragma unroll
  for (int j = 0; j < 8; ++j) bj[j] = bf2f(bias[j * 16 + fr]);

  const int Vt = Vtot >> 6;
#pragma unroll
  for (int rep = 0; rep < (NRB + 7) / 8; ++rep) {
    const int rb = rep * 8 + wid;
    if (rb < NRB) {
#pragma unroll
      for (int bb = 0; bb < 4; ++bb) {
        f32x4 acc2[8] = {};
#pragma unroll
        for (int ksi = 0; ksi < 2; ++ksi) {
          s16x8 af = *(const s16x8*)(smem + (rb * 16 + fr) * 264 + bb * 64 +
                                     ksi * 32 + q4 * 8);
#pragma unroll
          for (int j = 0; j < 8; ++j)
            acc2[j] = __builtin_amdgcn_mfma_f32_16x16x32_bf16(af, wf[ksi][j],
                                                              acc2[j], 0, 0, 0);
        }
        const int v = v0 + rb * 16 + q4 * 4;
#pragma unroll
        for (int j = 0; j < 4; ++j) {
          const int o = j * 16 + fr;
          const int hrow = m0 + bb * 64 + o;
          if constexpr (FUSEMAX) {
            // out[v+r][hrow] = max(GLU(acc2), H1[hrow][1024+v+r])
            const int c = 1024 + v;  // H1 col; Vt of H1 is 48
            u16x4 hv = *(const u16x4*)(Hprev +
                ((uint64_t)(hrow >> 6) * 48 + (c >> 6)) * 4096 +
                ((c >> 3) & 7) * 512 + (hrow & 63) * 8 + (c & 7));
            float* op = outp + (uint64_t)v * 4096 + hrow;
#pragma unroll
            for (int r = 0; r < 4; ++r) {
              float lhs = acc2[j][r] + bj[j];
              float rhs = acc2[j + 4][r] + bj[j + 4];
              float sg = 1.0f / (1.0f + __expf(-rhs));
              op[(uint64_t)r * 4096] = fmaxf(lhs * sg, bf2f(hv[r]));
            }
          } else {
            u16x4 pk;
#pragma unroll
            for (int r = 0; r < 4; ++r) {
              float lhs = acc2[j][r] + bj[j];
              float rhs = acc2[j + 4][r] + bj[j + 4];
              float sg = 1.0f / (1.0f + __expf(-rhs));
              pk[r] = f2bf(lhs * sg);
            }
            *(u16x4*)(H + ((uint64_t)(hrow >> 6) * Vt + (v >> 6)) * 4096 +
                      ((v >> 3) & 7) * 512 + (hrow & 63) * 8 + (v & 7)) = pk;
          }
        }
      }
    }
  }
}

// ---------------------------------------------------------------------------
extern "C" void kernel_launch(void* const* d_in, const int* in_sizes, int n_in,
                              void* d_out, int out_size, void* d_ws, size_t ws_size,
                              hipStream_t stream) {
  (void)in_sizes; (void)n_in; (void)out_size; (void)ws_size;
  const void* x  = d_in[0];  // [3072][64][64]
  const void* A  = d_in[1];  // [3072][3072]
  const void* W0 = d_in[2];  // [128][64]
  const void* b0 = d_in[3];  // [128]
  const void* W1 = d_in[4];  // [128][64]
  const void* b1 = d_in[5];  // [128]
  float* out = (float*)d_out;  // [1024][64][64] fp32

  char* ws = (char*)d_ws;
  unsigned short* Xtp = (unsigned short*)(ws + 0);         // 25165824 B
  unsigned short* Abp = (unsigned short*)(ws + 25165824);  // 18874368 B
  unsigned short* Wb  = (unsigned short*)(ws + 44040192);  // 33280 B
  unsigned short* H1p = (unsigned short*)(ws + 44105728);  // 25165824 B -> end 69271552

  // P0: transpose (3072 blocks) + packA (2304) + cvtW (1), detect folded in
  k_prep<<<5377, 256, 0, stream>>>(x, A, W0, b0, W1, b1, Xtp, Abp, Wb);
  // K1f: H1 = GLU(W0.(A.Xt^T)+b0), v covers 3072. 192x256 tiles -> 16x16 =
  // 256 blocks = exactly 1 per CU (full chip).
  k_gemm_glu4<192, 3072, false><<<dim3(16, 16), 512, 0, stream>>>(
      Abp, Xtp, Wb, Wb + 8192, H1p, nullptr, nullptr, 3072);
  // K3f+max: H2 = GLU(W1.(A[rows 1024+].H1^T)+b1) fused with
  // out = max(H1[., 1024+n], H2[., n]) -> fp32 out. 64x256 tiles, 256 blocks.
  k_gemm_glu4<64, 3072, true><<<dim3(16, 16), 512, 0, stream>>>(
      Abp + (uint64_t)16 * 48 * 4096, H1p, Wb + 8320, Wb + 16512,
      nullptr, H1p, out, 1024);
}